// Round 1
// baseline (286.224 us; speedup 1.0000x reference)
//
#include <hip/hip_runtime.h>

#ifndef GS_G
#define GS_G 256
#endif

// 3D grid_sample (trilinear, align_corners=True semantics per reference),
// volume shape (1,1,D,H,W) with D=H=W=256, points in [-1,1].
// One thread per point.
__global__ void __launch_bounds__(256) grid_sample_3d_kernel(
    const float* __restrict__ coords,   // (P,3)
    const float* __restrict__ vol,      // (D,H,W) = (256,256,256)
    float* __restrict__ out,            // (P)
    int P)
{
    int i = blockIdx.x * blockDim.x + threadIdx.x;
    if (i >= P) return;

    const int W = GS_G, H = GS_G, D = GS_G;

    float x = coords[3 * i + 0];
    float y = coords[3 * i + 1];
    float z = coords[3 * i + 2];

    // ix = (x+1)/2 * (W-1)
    float ix = (x + 1.0f) * 0.5f * (float)(W - 1);
    float iy = (y + 1.0f) * 0.5f * (float)(H - 1);
    float iz = (z + 1.0f) * 0.5f * (float)(D - 1);

    float x0f = floorf(ix);
    float y0f = floorf(iy);
    float z0f = floorf(iz);

    // Reference weights: (x1 - ix) = 1 - tx, (ix - x0) = tx with x1 = x0+1 (unclamped)
    float tx = ix - x0f;
    float ty = iy - y0f;
    float tz = iz - z0f;

    int x0 = (int)x0f;
    int y0 = (int)y0f;
    int z0 = (int)z0f;

    int cx0 = min(max(x0, 0), W - 1);
    int cx1 = min(max(x0 + 1, 0), W - 1);
    int cy0 = min(max(y0, 0), H - 1);
    int cy1 = min(max(y0 + 1, 0), H - 1);
    int cz0 = min(max(z0, 0), D - 1);
    int cz1 = min(max(z0 + 1, 0), D - 1);

    // Flat offsets
    int zy00 = (cz0 * H + cy0) * W;
    int zy01 = (cz0 * H + cy1) * W;
    int zy10 = (cz1 * H + cy0) * W;
    int zy11 = (cz1 * H + cy1) * W;

    float v000 = vol[zy00 + cx0];
    float v001 = vol[zy00 + cx1];
    float v010 = vol[zy01 + cx0];
    float v011 = vol[zy01 + cx1];
    float v100 = vol[zy10 + cx0];
    float v101 = vol[zy10 + cx1];
    float v110 = vol[zy11 + cx0];
    float v111 = vol[zy11 + cx1];

    // Factored trilinear lerp (numerically equivalent to reference's 8-weight sum
    // well within threshold).
    float wx0 = 1.0f - tx, wx1 = tx;
    float wy0 = 1.0f - ty, wy1 = ty;
    float wz0 = 1.0f - tz, wz1 = tz;

    float c00 = v000 * wx0 + v001 * wx1;
    float c01 = v010 * wx0 + v011 * wx1;
    float c10 = v100 * wx0 + v101 * wx1;
    float c11 = v110 * wx0 + v111 * wx1;

    float c0 = c00 * wy0 + c01 * wy1;
    float c1 = c10 * wy0 + c11 * wy1;

    out[i] = c0 * wz0 + c1 * wz1;
}

extern "C" void kernel_launch(void* const* d_in, const int* in_sizes, int n_in,
                              void* d_out, int out_size, void* d_ws, size_t ws_size,
                              hipStream_t stream) {
    const float* coords = (const float*)d_in[0];   // (P,3) fp32
    const float* vol    = (const float*)d_in[1];   // (1,1,256,256,256) fp32
    float* out          = (float*)d_out;           // (P,1) fp32

    int P = in_sizes[0] / 3;

    int block = 256;
    int grid = (P + block - 1) / block;
    grid_sample_3d_kernel<<<grid, block, 0, stream>>>(coords, vol, out, P);
}